// Round 1
// baseline (767.521 us; speedup 1.0000x reference)
//
#include <hip/hip_runtime.h>
#include <math.h>

#define HIDDEN 96
#define NNODES 50000
#define NEDGES 800000
#define INDIM  256
#define RS 0.07216878364870323f   // 1/sqrt(2*HIDDEN)

typedef float f32x4 __attribute__((ext_vector_type(4)));

// fast tanh: tanh(x) = sign(x) * (1 - 2/(1+exp2(2|x|*log2e)))
// hw v_exp_f32 + v_rcp_f32; abs err ~1e-6; saturates to +/-1 correctly.
__device__ __forceinline__ float fast_tanh(float x) {
    float e = __builtin_amdgcn_exp2f(fabsf(x) * 2.8853900817779268f);
    float t = 1.0f - 2.0f * __builtin_amdgcn_rcpf(1.0f + e);
    return copysignf(t, x);
}

// ---------------------------------------------------------------------------
// Repack W_gate [96][192] into V [192][96]: V[j][k] = Wg[j][k]*RS (j<96),
// V[96+j][k] = Wg[j][96+k]*RS; bias2 = [b_gate*RS, 0].
// ---------------------------------------------------------------------------
__global__ void repack_kernel(const float* __restrict__ Wg, const float* __restrict__ bg,
                              float* __restrict__ V, float* __restrict__ bias2) {
    int idx = blockIdx.x * 256 + threadIdx.x;
    if (idx < 192 * 96) {
        int j = idx / 96, k = idx % 96;
        float v = (j < 96) ? Wg[j * 192 + k] : Wg[(j - 96) * 192 + 96 + k];
        V[idx] = v * RS;
    }
    if (idx < 192) bias2[idx] = (idx < 96) ? bg[idx] * RS : 0.0f;
}

// ---------------------------------------------------------------------------
// Generic C[M][ldc] = A[M][K](lda) @ B[96][K]^T + bias. BM=128, BN=96, BK=32,
// 256 thr, 8x6 micro-tile. Used for gemm1 (h = x@W_in^T -> SH[:,96:192]).
// ---------------------------------------------------------------------------
__global__ __launch_bounds__(256) void gemm_nt_bias(
    const float* __restrict__ A, int lda,
    const float* __restrict__ B,
    const float* __restrict__ bias, float* __restrict__ C,
    int M, int K, int ldc) {
    __shared__ float As[128][36];
    __shared__ float Bs[96][36];
    const int tid = threadIdx.x;
    const int m0 = blockIdx.x * 128;
    const int te = tid >> 4;
    const int tc = tid & 15;
    const int ra = tid >> 3;
    const int ka = (tid & 7) * 4;

    float acc[8][6];
#pragma unroll
    for (int i = 0; i < 8; i++)
#pragma unroll
        for (int j = 0; j < 6; j++) acc[i][j] = 0.0f;

    for (int k0 = 0; k0 < K; k0 += 32) {
#pragma unroll
        for (int r = 0; r < 4; r++) {
            int row = m0 + ra + r * 32;
            float4 v = make_float4(0, 0, 0, 0);
            if (row < M) v = *(const float4*)&A[(size_t)row * lda + k0 + ka];
            *(float4*)&As[ra + r * 32][ka] = v;
        }
#pragma unroll
        for (int r = 0; r < 3; r++) {
            int row = ra + r * 32;
            float4 v = *(const float4*)&B[(size_t)row * K + k0 + ka];
            *(float4*)&Bs[row][ka] = v;
        }
        __syncthreads();
#pragma unroll
        for (int k4 = 0; k4 < 32; k4 += 4) {
            float4 af[8], bf[6];
#pragma unroll
            for (int i = 0; i < 8; i++) af[i] = *(float4*)&As[8 * te + i][k4];
#pragma unroll
            for (int j = 0; j < 6; j++) bf[j] = *(float4*)&Bs[6 * tc + j][k4];
#pragma unroll
            for (int i = 0; i < 8; i++)
#pragma unroll
                for (int j = 0; j < 6; j++)
                    acc[i][j] += af[i].x * bf[j].x + af[i].y * bf[j].y +
                                 af[i].z * bf[j].z + af[i].w * bf[j].w;
        }
        __syncthreads();
    }
#pragma unroll
    for (int i = 0; i < 8; i++) {
        int row = m0 + 8 * te + i;
        if (row < M) {
#pragma unroll
            for (int j = 0; j < 6; j++) {
                int col = 6 * tc + j;
                C[(size_t)row * ldc + col] = acc[i][j] + bias[col];
            }
        }
    }
}

// ---------------------------------------------------------------------------
// gemm2 dual-output: A = SH+96 (h, lda=192), K=96.
//   blockIdx.y==0: D[:,0:96]  = h @ V[0:96]^T  + b2[0:96]   (pd part, ldc 96)
//   blockIdx.y==1: SH[:,0:96] = h @ V[96:192]^T + 0          (ps part, ldc 192)
// ---------------------------------------------------------------------------
__global__ __launch_bounds__(256) void gemm2_dual(
    const float* __restrict__ Ah,    // SH + 96, lda 192
    const float* __restrict__ V,     // [192][96]
    const float* __restrict__ b2,    // [192]
    float* __restrict__ Dm,          // [M][96]
    float* __restrict__ SH,          // [M][192]
    int M) {
    __shared__ float As[128][36];
    __shared__ float Bs[96][36];
    const int tid = threadIdx.x;
    const int m0 = blockIdx.x * 128;
    const int half = blockIdx.y;
    const int n0 = half * 96;
    const int te = tid >> 4;
    const int tc = tid & 15;
    const int ra = tid >> 3;
    const int ka = (tid & 7) * 4;

    float acc[8][6];
#pragma unroll
    for (int i = 0; i < 8; i++)
#pragma unroll
        for (int j = 0; j < 6; j++) acc[i][j] = 0.0f;

    for (int k0 = 0; k0 < 96; k0 += 32) {
#pragma unroll
        for (int r = 0; r < 4; r++) {
            int row = m0 + ra + r * 32;
            float4 v = make_float4(0, 0, 0, 0);
            if (row < M) v = *(const float4*)&Ah[(size_t)row * 192 + k0 + ka];
            *(float4*)&As[ra + r * 32][ka] = v;
        }
#pragma unroll
        for (int r = 0; r < 3; r++) {
            int row = ra + r * 32;
            float4 v = *(const float4*)&V[(size_t)(n0 + row) * 96 + k0 + ka];
            *(float4*)&Bs[row][ka] = v;
        }
        __syncthreads();
#pragma unroll
        for (int k4 = 0; k4 < 32; k4 += 4) {
            float4 af[8], bf[6];
#pragma unroll
            for (int i = 0; i < 8; i++) af[i] = *(float4*)&As[8 * te + i][k4];
#pragma unroll
            for (int j = 0; j < 6; j++) bf[j] = *(float4*)&Bs[6 * tc + j][k4];
#pragma unroll
            for (int i = 0; i < 8; i++)
#pragma unroll
                for (int j = 0; j < 6; j++)
                    acc[i][j] += af[i].x * bf[j].x + af[i].y * bf[j].y +
                                 af[i].z * bf[j].z + af[i].w * bf[j].w;
        }
        __syncthreads();
    }
    float* Cp = half ? SH : Dm;
    const int ldc = half ? 192 : 96;
#pragma unroll
    for (int i = 0; i < 8; i++) {
        int row = m0 + 8 * te + i;
        if (row < M) {
#pragma unroll
            for (int j = 0; j < 6; j++) {
                int col = 6 * tc + j;
                Cp[(size_t)row * ldc + col] = acc[i][j] + b2[n0 + col];
            }
        }
    }
}

// ---------------------------------------------------------------------------
// CSR build: histogram of dst -> block scan -> scatter (e,src) pairs.
// ---------------------------------------------------------------------------
__global__ void hist_kernel(const int* __restrict__ dst, int* __restrict__ counts) {
    int i = blockIdx.x * 256 + threadIdx.x;
    if (i < NEDGES) atomicAdd(&counts[dst[i]], 1);
}

__global__ __launch_bounds__(512) void scan1_kernel(const int* __restrict__ counts,
                                                    int* __restrict__ offsets,
                                                    int* __restrict__ btot) {
    __shared__ int sh[512];
    int tid = threadIdx.x;
    int i = blockIdx.x * 512 + tid;
    int v = (i < NNODES) ? counts[i] : 0;
    sh[tid] = v;
    __syncthreads();
    for (int off = 1; off < 512; off <<= 1) {
        int tmp = 0;
        if (tid >= off) tmp = sh[tid - off];
        __syncthreads();
        if (tid >= off) sh[tid] += tmp;
        __syncthreads();
    }
    if (i < NNODES) offsets[i] = sh[tid] - v;
    if (tid == 511) btot[blockIdx.x] = sh[511];
}

__global__ __launch_bounds__(128) void scan2_kernel(int* __restrict__ btot, int nb) {
    __shared__ int sh[128];
    int tid = threadIdx.x;
    int v = (tid < nb) ? btot[tid] : 0;
    sh[tid] = v;
    __syncthreads();
    for (int off = 1; off < 128; off <<= 1) {
        int tmp = 0;
        if (tid >= off) tmp = sh[tid - off];
        __syncthreads();
        if (tid >= off) sh[tid] += tmp;
        __syncthreads();
    }
    if (tid < nb) btot[tid] = sh[tid] - v;
}

__global__ __launch_bounds__(512) void scan3_kernel(int* __restrict__ offsets,
                                                    const int* __restrict__ btot) {
    int i = blockIdx.x * 512 + threadIdx.x;
    if (i < NNODES) offsets[i] += btot[blockIdx.x];
    if (i == 0) offsets[NNODES] = NEDGES;
}

__global__ void scatter_kernel(const int* __restrict__ src, const int* __restrict__ dst,
                               const int* __restrict__ offsets, int* __restrict__ cursor,
                               int2* __restrict__ epair) {
    int e = blockIdx.x * 256 + threadIdx.x;
    if (e < NEDGES) {
        int t = dst[e];
        int pos = offsets[t] + atomicAdd(&cursor[t], 1);
        epair[pos] = make_int2(e, src[e]);
    }
}

// ---------------------------------------------------------------------------
// Aggregation: 24-lane group per dst node (float4 chunk per lane).
// SH[s] = [ps(96) | h(96)] -> one contiguous 768B gather region per edge.
// a_out stores are non-temporal (307MB stream must not evict SH/D from L2/L3).
// ---------------------------------------------------------------------------
#define GPB 32
#define TPG 24
__global__ __launch_bounds__(768) void agg_kernel(
    const float* __restrict__ Dm, const float* __restrict__ SH,
    const float* __restrict__ dvec, const int* __restrict__ offsets,
    const int2* __restrict__ epair,
    const float* __restrict__ Wc, const float* __restrict__ bc,
    float* __restrict__ a_out, float* __restrict__ z_out) {
    __shared__ float red0[GPB * TPG];
    __shared__ float red1[GPB * TPG];
    const int t = threadIdx.x;
    const int g = t / TPG;
    const int c = t % TPG;
    const int node = blockIdx.x * GPB + g;
    float s0 = 0.0f, s1 = 0.0f;
    if (node < NNODES) {
        float4 pd = *(const float4*)&Dm[(size_t)node * 96 + 4 * c];
        float dt = dvec[node];
        int start = offsets[node], end = offsets[node + 1];
        float4 z4 = make_float4(0, 0, 0, 0);
        for (int i = start; i < end; i++) {
            int2 ep = epair[i];
            const float* base = &SH[(size_t)ep.y * 192];
            float4 ps = *(const float4*)(base + 4 * c);
            float4 hs = *(const float4*)(base + 96 + 4 * c);
            float ee = dt * dvec[ep.y];
            f32x4 a4;
            a4.x = fast_tanh(pd.x + ps.x);
            a4.y = fast_tanh(pd.y + ps.y);
            a4.z = fast_tanh(pd.z + ps.z);
            a4.w = fast_tanh(pd.w + ps.w);
            __builtin_nontemporal_store(a4, (f32x4*)&a_out[(size_t)ep.x * 96 + 4 * c]);
            z4.x += hs.x * a4.x * ee;
            z4.y += hs.y * a4.y * ee;
            z4.z += hs.z * a4.z * ee;
            z4.w += hs.w * a4.w * ee;
        }
        float4 w0 = *(const float4*)&Wc[4 * c];
        float4 w1 = *(const float4*)&Wc[96 + 4 * c];
        s0 = z4.x * w0.x + z4.y * w0.y + z4.z * w0.z + z4.w * w0.w;
        s1 = z4.x * w1.x + z4.y * w1.y + z4.z * w1.z + z4.w * w1.w;
    }
    red0[t] = s0;
    red1[t] = s1;
    __syncthreads();
    if (c == 0 && node < NNODES) {
        float a0 = bc[0], a1 = bc[1];
#pragma unroll
        for (int k = 0; k < TPG; k++) { a0 += red0[t + k]; a1 += red1[t + k]; }
        float m = fmaxf(a0, a1);
        float lse = m + logf(expf(a0 - m) + expf(a1 - m));
        z_out[2 * node + 0] = a0 - lse;
        z_out[2 * node + 1] = a1 - lse;
    }
}

extern "C" void kernel_launch(void* const* d_in, const int* in_sizes, int n_in,
                              void* d_out, int out_size, void* d_ws, size_t ws_size,
                              hipStream_t stream) {
    const float* x    = (const float*)d_in[0];
    const float* dvec = (const float*)d_in[1];
    const int*   src  = (const int*)d_in[2];
    const int*   dst  = (const int*)d_in[3];
    const float* W_in = (const float*)d_in[4];
    const float* b_in = (const float*)d_in[5];
    const float* W_g  = (const float*)d_in[6];
    const float* b_g  = (const float*)d_in[7];
    const float* W_c  = (const float*)d_in[8];
    const float* b_c  = (const float*)d_in[9];

    float* z_out = (float*)d_out;                 // [50000*2]
    float* a_out = (float*)d_out + 2 * NNODES;    // [800000*96]

    char* ws = (char*)d_ws;
    float* SH      = (float*)(ws);                 // [50K][192] = 38,400,000 B
    float* Dm      = (float*)(ws + 38400000);      // [50K][96]  = 19,200,000 B
    float* V       = (float*)(ws + 57600000);      // 73,728 B
    float* b2      = (float*)(ws + 57673728);      // 1,024 B (768 used)
    int*   offsets = (int*)  (ws + 57674752);      // 200,064 B (50001 used)
    int*   counts  = (int*)  (ws + 57874816);      // 200,064 B
    int*   cursor  = (int*)  (ws + 58074880);      // 200,064 B
    int*   btot    = (int*)  (ws + 58274944);      // 512 B (98 used)
    int2*  epair   = (int2*) (ws + 58275456);      // 6,400,000 B
    // total 64,675,456 B (same as previous layout)

    hipMemsetAsync(counts, 0, NNODES * sizeof(int), stream);
    hipMemsetAsync(cursor, 0, NNODES * sizeof(int), stream);

    repack_kernel<<<dim3((192 * 96 + 255) / 256), 256, 0, stream>>>(W_g, b_g, V, b2);
    // h = x @ W_in.T + b_in  -> SH[:,96:192]  (ldc 192)
    gemm_nt_bias<<<dim3((NNODES + 127) / 128), 256, 0, stream>>>(
        x, INDIM, W_in, b_in, SH + 96, NNODES, INDIM, 192);
    // pd -> Dm, ps -> SH[:,0:96]
    gemm2_dual<<<dim3((NNODES + 127) / 128, 2), 256, 0, stream>>>(
        SH + 96, V, b2, Dm, SH, NNODES);

    // CSR by dst
    const int NB = (NNODES + 511) / 512;  // 98
    hist_kernel<<<dim3((NEDGES + 255) / 256), 256, 0, stream>>>(dst, counts);
    scan1_kernel<<<dim3(NB), 512, 0, stream>>>(counts, offsets, btot);
    scan2_kernel<<<dim3(1), 128, 0, stream>>>(btot, NB);
    scan3_kernel<<<dim3(NB), 512, 0, stream>>>(offsets, btot);
    scatter_kernel<<<dim3((NEDGES + 255) / 256), 256, 0, stream>>>(src, dst, offsets, cursor, epair);

    // Edge pass + scatter-free aggregation + fused classifier/log_softmax
    agg_kernel<<<dim3((NNODES + GPB - 1) / GPB), GPB * TPG, 0, stream>>>(
        Dm, SH, dvec, offsets, epair, W_c, b_c, a_out, z_out);
}